// Round 3
// baseline (234.895 us; speedup 1.0000x reference)
//
#include <hip/hip_runtime.h>
#include <math.h>

#define HID 128
#define TILE_R 64
#define XS_STRIDE 132      // fp32 staging stride (K1)
#define H0S_STRIDE 136     // bf16 h0 stride in shorts (K2): 272 B = 68 dwords == 4 mod 32 banks
#define DELTA 0.05f        // |s_bf16 - s_exact| bound (~50 sigma); candidates expected ~2-3

typedef short bf16x8 __attribute__((ext_vector_type(8)));
typedef float f32x4 __attribute__((ext_vector_type(4)));

static __device__ __forceinline__ unsigned short f2bf(float f) {
    union { float f; unsigned u; } v; v.f = f;
    unsigned r = v.u + 0x7FFFu + ((v.u >> 16) & 1u);   // RNE
    return (unsigned short)(r >> 16);
}
static __device__ __forceinline__ float bflo(unsigned u) {
    union { unsigned u; float f; } v; v.u = u << 16; return v.f;
}
static __device__ __forceinline__ float bfhi(unsigned u) {
    union { unsigned u; float f; } v; v.u = u & 0xFFFF0000u; return v.f;
}

#define FMA4(avc, wv)                         \
    acc[r][0] = fmaf(avc, wv.x, acc[r][0]);   \
    acc[r][1] = fmaf(avc, wv.y, acc[r][1]);   \
    acc[r][2] = fmaf(avc, wv.z, acc[r][2]);   \
    acc[r][3] = fmaf(avc, wv.w, acc[r][3]);

// ---------------------------------------------------------------------------
// K1: g[128] = x_graph @ W0[0:256] + b0 (fp32, exact — rescue depends on it)
//     Pbf = bf16( [x_m @ W0[256:384] ; x_job @ W0[384:512]] )
//     W1T[n*128+k] = bf16(W1[k][n])   (MFMA B-fragment friendly)
//     + zero the atomic counters / packed argmax
// ---------------------------------------------------------------------------
__global__ __launch_bounds__(256, 4) void precompute_kernel(
    const float* __restrict__ x_graph,
    const float* __restrict__ x_m,
    const float* __restrict__ x_job,
    const float* __restrict__ W0,
    const float* __restrict__ b0,
    const float* __restrict__ W1,
    float* __restrict__ g,
    unsigned short* __restrict__ Pbf,
    unsigned short* __restrict__ W1T,
    unsigned* __restrict__ miscu,
    int M, int J, int aTiles, int bTiles)
{
    const int t = threadIdx.x;
    const int bid = blockIdx.x;

    if (bid == 0) {
        if (t == 0) { miscu[0] = 0u; miscu[1] = 0u; miscu[2] = 0u; miscu[3] = 0u; }
        __shared__ float xg[2 * HID];
        if (t < HID) { xg[t] = x_graph[t]; xg[t + HID] = x_graph[t + HID]; }
        __syncthreads();
        if (t < HID) {
            float acc = b0[t];
            #pragma unroll 8
            for (int k = 0; k < 2 * HID; ++k)
                acc = fmaf(xg[k], W0[k * HID + t], acc);
            g[t] = acc;
        }
        return;
    }
    if (bid == 1 + aTiles + bTiles) {
        for (int e = t; e < HID * HID; e += 256) {
            int n = e >> 7, k = e & 127;
            W1T[e] = f2bf(W1[k * HID + n]);
        }
        return;
    }

    const int tb = bid - 1;
    const float* X;
    const float* W;
    int r0, nr, dstBase;
    if (tb < aTiles) {
        r0 = tb * TILE_R;
        nr = min(TILE_R, M - r0);
        X = x_m + (size_t)r0 * HID;
        W = W0 + 2 * HID * HID;
        dstBase = r0;
    } else {
        int jb = tb - aTiles;
        r0 = jb * TILE_R;
        nr = min(TILE_R, J - r0);
        X = x_job + (size_t)r0 * HID;
        W = W0 + 3 * HID * HID;
        dstBase = M + r0;
    }

    __shared__ float xs[TILE_R * XS_STRIDE];
    {
        int row = t >> 2;
        int q = t & 3;
        #pragma unroll
        for (int u = 0; u < 8; ++u) {
            int c = q * 32 + u * 4;
            float4 v = (row < nr) ? *(const float4*)(X + row * HID + c)
                                  : make_float4(0.f, 0.f, 0.f, 0.f);
            *(float4*)&xs[row * XS_STRIDE + c] = v;
        }
    }
    __syncthreads();

    const int w = t >> 6;
    const int l = t & 63;
    const int tc = l & 7;
    const int tr = l >> 3;
    const int c0 = w * 32 + tc * 4;

    float acc[8][4];
    #pragma unroll
    for (int r = 0; r < 8; ++r)
        #pragma unroll
        for (int c = 0; c < 4; ++c) acc[r][c] = 0.0f;

    #pragma unroll 2
    for (int k0 = 0; k0 < HID; k0 += 4) {
        float4 w0v = *(const float4*)(W + (k0 + 0) * HID + c0);
        float4 w1v = *(const float4*)(W + (k0 + 1) * HID + c0);
        float4 w2m = *(const float4*)(W + (k0 + 2) * HID + c0);
        float4 w3v = *(const float4*)(W + (k0 + 3) * HID + c0);
        #pragma unroll
        for (int r = 0; r < 8; ++r) {
            float4 a = *(const float4*)&xs[(r * 8 + tr) * XS_STRIDE + k0];
            FMA4(a.x, w0v)
            FMA4(a.y, w1v)
            FMA4(a.z, w2m)
            FMA4(a.w, w3v)
        }
    }

    #pragma unroll
    for (int r = 0; r < 8; ++r) {
        int row = r * 8 + tr;
        if (row < nr) {
            unsigned lo0 = (unsigned)f2bf(acc[r][0]) | ((unsigned)f2bf(acc[r][1]) << 16);
            unsigned lo1 = (unsigned)f2bf(acc[r][2]) | ((unsigned)f2bf(acc[r][3]) << 16);
            uint2 pk = make_uint2(lo0, lo1);
            *(uint2*)(Pbf + (size_t)(dstBase + row) * HID + c0) = pk;
        }
    }
}

// ---------------------------------------------------------------------------
// softmax-partial merge helper
// ---------------------------------------------------------------------------
__device__ inline void sm_merge(float& am, float& az, float& ass, int& ai,
                                float bm, float bz, float bss, int bi)
{
    if (bm > am || (bm == am && bi < ai)) {
        float tm = am, tz = az, ts = ass; int ti = ai;
        am = bm; az = bz; ass = bss; ai = bi;
        bm = tm; bz = tz; bss = ts; bi = ti;
    }
    float f = expf(bm - am);
    az += bz * f;
    ass += (bss + (bm - am) * bz) * f;
}

// ---------------------------------------------------------------------------
// K2: per 64-row tile:
//   h0 = bf16(relu(g + Pbf[m] + Pbf[M+j])) staged in LDS as MFMA-A fragments,
//   h1 tile via mfma_f32_16x16x32_bf16 (wave w -> rows w*16..+16, all 128 cols),
//   fused relu+b1, dot W2 -> per-row score; scores[] + per-block softmax partial.
//   Last block to finish merges all partials -> out[3], ws{mhat, z}.
// ---------------------------------------------------------------------------
__global__ __launch_bounds__(256, 4) void main_kernel(
    const int* __restrict__ m_ids,
    const int* __restrict__ job_idx,
    const float* __restrict__ b1,
    const float* __restrict__ W2,
    const float* __restrict__ b2,
    const float* __restrict__ g,
    const unsigned short* __restrict__ Pbf,
    const unsigned short* __restrict__ W1T,
    float* __restrict__ scores,
    float4* __restrict__ partials,
    unsigned* __restrict__ miscu,
    float* __restrict__ miscf,
    float* __restrict__ out,
    int N, int M)
{
    __shared__ __align__(16) short h0s[TILE_R * H0S_STRIDE];
    __shared__ float sred[TILE_R];
    __shared__ int lastFlag;

    const int t = threadIdx.x;
    const int row0 = blockIdx.x * TILE_R;

    // ---- stage h0 (bf16): thread t -> row t/4, 32-col quarter t%4 ----
    {
        int row = t >> 2;
        int q = t & 3;
        int grow = row0 + row;
        int gr = (grow < N) ? grow : (N - 1);
        int m = m_ids[gr];
        int j = job_idx[gr];
        const unsigned short* pm = Pbf + (size_t)m * HID + q * 32;
        const unsigned short* pj = Pbf + (size_t)(M + j) * HID + q * 32;
        const float* gp = g + q * 32;
        short* dst = &h0s[row * H0S_STRIDE + q * 32];
        #pragma unroll
        for (int u = 0; u < 4; ++u) {
            uint4 mv = *(const uint4*)(pm + u * 8);
            uint4 jv = *(const uint4*)(pj + u * 8);
            float4 g0 = *(const float4*)(gp + u * 8);
            float4 g1 = *(const float4*)(gp + u * 8 + 4);
            float h0v = fmaxf(bflo(mv.x) + bflo(jv.x) + g0.x, 0.f);
            float h1v = fmaxf(bfhi(mv.x) + bfhi(jv.x) + g0.y, 0.f);
            float h2v = fmaxf(bflo(mv.y) + bflo(jv.y) + g0.z, 0.f);
            float h3v = fmaxf(bfhi(mv.y) + bfhi(jv.y) + g0.w, 0.f);
            float h4v = fmaxf(bflo(mv.z) + bflo(jv.z) + g1.x, 0.f);
            float h5v = fmaxf(bfhi(mv.z) + bfhi(jv.z) + g1.y, 0.f);
            float h6v = fmaxf(bflo(mv.w) + bflo(jv.w) + g1.z, 0.f);
            float h7v = fmaxf(bfhi(mv.w) + bfhi(jv.w) + g1.w, 0.f);
            uint4 pk;
            pk.x = (unsigned)f2bf(h0v) | ((unsigned)f2bf(h1v) << 16);
            pk.y = (unsigned)f2bf(h2v) | ((unsigned)f2bf(h3v) << 16);
            pk.z = (unsigned)f2bf(h4v) | ((unsigned)f2bf(h5v) << 16);
            pk.w = (unsigned)f2bf(h6v) | ((unsigned)f2bf(h7v) << 16);
            *(uint4*)(dst + u * 8) = pk;
        }
    }
    __syncthreads();

    // ---- MFMA: wave w computes rows [w*16, w*16+16) x cols [0,128) ----
    const int l = t & 63;
    const int w = t >> 6;
    const int quad = l >> 4;
    const int mrow = l & 15;

    bf16x8 af[4];
    const short* ab = &h0s[(w * 16 + mrow) * H0S_STRIDE + quad * 8];
    #pragma unroll
    for (int kc = 0; kc < 4; ++kc)
        af[kc] = *(const bf16x8*)(ab + kc * 32);

    f32x4 acc[8];
    #pragma unroll
    for (int nt = 0; nt < 8; ++nt) {
        f32x4 z = {0.f, 0.f, 0.f, 0.f};
        acc[nt] = z;
    }

    const unsigned short* bb = W1T + (size_t)mrow * HID + quad * 8;
    #pragma unroll
    for (int nt = 0; nt < 8; ++nt) {
        #pragma unroll
        for (int kc = 0; kc < 4; ++kc) {
            bf16x8 bfr = *(const bf16x8*)(bb + nt * 16 * HID + kc * 32);
            acc[nt] = __builtin_amdgcn_mfma_f32_16x16x32_bf16(af[kc], bfr, acc[nt], 0, 0, 0);
        }
    }

    // ---- epilogue: relu+b1, dot W2; reduce across the 16 col-lanes ----
    float p0 = 0.f, p1 = 0.f, p2 = 0.f, p3 = 0.f;
    #pragma unroll
    for (int nt = 0; nt < 8; ++nt) {
        int c = nt * 16 + mrow;
        float b1v = b1[c], w2v = W2[c];
        p0 += fmaxf(acc[nt][0] + b1v, 0.f) * w2v;
        p1 += fmaxf(acc[nt][1] + b1v, 0.f) * w2v;
        p2 += fmaxf(acc[nt][2] + b1v, 0.f) * w2v;
        p3 += fmaxf(acc[nt][3] + b1v, 0.f) * w2v;
    }
    #pragma unroll
    for (int off = 1; off < 16; off <<= 1) {
        p0 += __shfl_xor(p0, off);
        p1 += __shfl_xor(p1, off);
        p2 += __shfl_xor(p2, off);
        p3 += __shfl_xor(p3, off);
    }
    if (mrow == 0) {
        int rb = w * 16 + quad * 4;
        sred[rb + 0] = p0;
        sred[rb + 1] = p1;
        sred[rb + 2] = p2;
        sred[rb + 3] = p3;
    }
    __syncthreads();

    // ---- wave 0: scores + per-block online-softmax partial ----
    if (t < 64) {
        int grow = row0 + t;
        float s = sred[t] + b2[0];
        if (grow < N) scores[grow] = s;
        else s = -1e30f;

        float mmax = s;
        int midx = grow;
        #pragma unroll
        for (int off = 1; off < 64; off <<= 1) {
            float om = __shfl_xor(mmax, off);
            int oi = __shfl_xor(midx, off);
            if (om > mmax || (om == mmax && oi < midx)) { mmax = om; midx = oi; }
        }
        float d = s - mmax;
        float e = expf(d);
        float z = e;
        float ss = d * e;
        #pragma unroll
        for (int off = 1; off < 64; off <<= 1) {
            z += __shfl_xor(z, off);
            ss += __shfl_xor(ss, off);
        }
        if (t == 0)
            partials[blockIdx.x] = make_float4(mmax, z, ss, (float)midx);
    }

    // ---- last-block merge of all partials ----
    if (t == 0) {
        __threadfence();
        unsigned old = atomicAdd(&miscu[0], 1u);
        lastFlag = (old == (unsigned)(gridDim.x - 1)) ? 1 : 0;
    }
    __syncthreads();
    if (lastFlag) {
        __threadfence();
        float m = -1e30f, z = 0.0f, ss = 0.0f;
        int idx = 0x7fffffff;
        int nparts = (int)gridDim.x;
        for (int i = t; i < nparts; i += 256) {
            float4 p = partials[i];
            sm_merge(m, z, ss, idx, p.x, p.y, p.z, (int)p.w);
        }
        #pragma unroll
        for (int off = 1; off < 64; off <<= 1) {
            float om = __shfl_xor(m, off);
            float oz = __shfl_xor(z, off);
            float os = __shfl_xor(ss, off);
            int oi = __shfl_xor(idx, off);
            sm_merge(m, z, ss, idx, om, oz, os, oi);
        }
        __shared__ float4 wred[4];
        __shared__ int widx[4];
        if ((t & 63) == 0) { wred[t >> 6] = make_float4(m, z, ss, 0.f); widx[t >> 6] = idx; }
        __syncthreads();
        if (t == 0) {
            for (int i = 1; i < 4; ++i)
                sm_merge(m, z, ss, idx, wred[i].x, wred[i].y, wred[i].z, widx[i]);
            out[3] = logf(z) - ss / z;   // entropy (bf16-path: err ~1e-3 << threshold)
            miscf[4] = m;                // mhat
            miscf[5] = z;                // Z relative to mhat
        }
    }
}

// ---------------------------------------------------------------------------
// K4: candidate scan + exact fp32 rescore + final argmax outputs.
//   Candidates: scores[i] >= mhat - DELTA (the true argmax is provably included).
//   Exact score recomputed from g (fp32), x_m/x_job @ W0 (fp32), W1/W2 (fp32).
//   Packed atomicMax key: (monotone float << 32) | (~idx) -> min-idx tie-break,
//   matching np.argmax first-occurrence for exact-duplicate rows.
// ---------------------------------------------------------------------------
__global__ __launch_bounds__(256) void select_kernel(
    const float* __restrict__ scores,
    const int* __restrict__ m_ids,
    const int* __restrict__ job_idx,
    const float* __restrict__ x_m,
    const float* __restrict__ x_job,
    const float* __restrict__ W0,
    const float* __restrict__ W1,
    const float* __restrict__ b1,
    const float* __restrict__ W2,
    const float* __restrict__ b2,
    const float* __restrict__ g,
    float* __restrict__ miscf,
    unsigned* __restrict__ miscu,
    float* __restrict__ out,
    int N, int M)
{
    __shared__ int cand[256];
    __shared__ int ccount;
    __shared__ float h0sh[HID];
    __shared__ float wred[4];

    const int t = threadIdx.x;
    if (t == 0) ccount = 0;
    __syncthreads();

    const float mhat = miscf[4];
    int i = blockIdx.x * 256 + t;
    if (i < N && scores[i] >= mhat - DELTA) {
        int p = atomicAdd(&ccount, 1);
        cand[p] = i;
    }
    __syncthreads();

    for (int c = 0; c < ccount; ++c) {
        int gr = cand[c];
        int m = m_ids[gr];
        int j = job_idx[gr];
        if (t < HID) {
            float acc = g[t];
            const float* wm = W0 + 2 * HID * HID;
            const float* wj = W0 + 3 * HID * HID;
            const float* xm = x_m + (size_t)m * HID;
            const float* xj = x_job + (size_t)j * HID;
            for (int k = 0; k < HID; ++k) {
                acc = fmaf(xm[k], wm[k * HID + t], acc);
                acc = fmaf(xj[k], wj[k * HID + t], acc);
            }
            h0sh[t] = fmaxf(acc, 0.f);
        }
        __syncthreads();
        int col = t >> 1, half = t & 1;
        float p = 0.f;
        for (int k = half * 64; k < half * 64 + 64; ++k)
            p = fmaf(h0sh[k], W1[k * HID + col], p);
        p += __shfl_xor(p, 1);
        float pp = (half == 0) ? fmaxf(p + b1[col], 0.f) * W2[col] : 0.f;
        #pragma unroll
        for (int off = 1; off < 64; off <<= 1)
            pp += __shfl_xor(pp, off);
        if ((t & 63) == 0) wred[t >> 6] = pp;
        __syncthreads();
        if (t == 0) {
            float s = wred[0] + wred[1] + wred[2] + wred[3] + b2[0];
            unsigned u = __float_as_uint(s);
            unsigned mono = (u & 0x80000000u) ? ~u : (u | 0x80000000u);
            unsigned long long key =
                ((unsigned long long)mono << 32) | (unsigned long long)(0xFFFFFFFFu - (unsigned)gr);
            atomicMax((unsigned long long*)&miscu[2], key);
        }
        __syncthreads();
    }

    if (t == 0) {
        __threadfence();
        unsigned old = atomicAdd(&miscu[1], 1u);
        if (old == (unsigned)(gridDim.x - 1)) {
            unsigned long long key = atomicMax((unsigned long long*)&miscu[2], 0ULL); // coherent read
            unsigned mono = (unsigned)(key >> 32);
            unsigned uu = (mono & 0x80000000u) ? (mono & 0x7FFFFFFFu) : ~mono;
            float swin = __uint_as_float(uu);
            int idx = (int)(0xFFFFFFFFu - (unsigned)(key & 0xFFFFFFFFu));
            float z = miscf[5];
            out[0] = (float)idx;
            out[1] = expf(swin - mhat) / z;
            out[2] = (swin - mhat) - logf(z);
        }
    }
}

// ---------------------------------------------------------------------------
extern "C" void kernel_launch(void* const* d_in, const int* in_sizes, int n_in,
                              void* d_out, int out_size, void* d_ws, size_t ws_size,
                              hipStream_t stream)
{
    const float* x_graph = (const float*)d_in[0];
    const float* x_m     = (const float*)d_in[1];
    const float* x_job   = (const float*)d_in[2];
    const int*   m_ids   = (const int*)d_in[3];
    const int*   job_idx = (const int*)d_in[4];
    const float* W0      = (const float*)d_in[5];
    const float* b0      = (const float*)d_in[6];
    const float* W1      = (const float*)d_in[7];
    const float* b1      = (const float*)d_in[8];
    const float* W2      = (const float*)d_in[9];
    const float* b2      = (const float*)d_in[10];
    float* out = (float*)d_out;

    const int N = in_sizes[3];
    const int M = in_sizes[1] / HID;
    const int J = in_sizes[2] / HID;

    const int tiles = (N + TILE_R - 1) / TILE_R;         // 3125
    const int aTiles = (M + TILE_R - 1) / TILE_R;        // 16
    const int bTiles = (J + TILE_R - 1) / TILE_R;        // 79

    // ws layout (all 16-B aligned):
    float* ws = (float*)d_ws;
    float* g = ws;                                        // 128 f
    float* scores = ws + HID;                             // N f
    float4* partials = (float4*)(scores + N);             // tiles f4
    float* miscf = (float*)(partials + tiles);            // 16 f (miscu overlays [0..3])
    unsigned* miscu = (unsigned*)miscf;
    unsigned short* W1T = (unsigned short*)(miscf + 16);  // HID*HID shorts
    unsigned short* Pbf = W1T + HID * HID;                // (M+J)*HID shorts

    precompute_kernel<<<1 + aTiles + bTiles + 1, 256, 0, stream>>>(
        x_graph, x_m, x_job, W0, b0, W1, g, Pbf, W1T, miscu, M, J, aTiles, bTiles);
    main_kernel<<<tiles, 256, 0, stream>>>(
        m_ids, job_idx, b1, W2, b2, g, Pbf, W1T, scores, partials,
        miscu, miscf, out, N, M);
    const int sblocks = (N + 255) / 256;                  // 782
    select_kernel<<<sblocks, 256, 0, stream>>>(
        scores, m_ids, job_idx, x_m, x_job, W0, W1, b1, W2, b2, g,
        miscf, miscu, out, N, M);
}